// Round 17
// baseline (863.361 us; speedup 1.0000x reference)
//
#include <hip/hip_runtime.h>
#include <hip/hip_bf16.h>

#define NN 100000
#define EE 500000

typedef __attribute__((ext_vector_type(8))) short short8v;
typedef __attribute__((ext_vector_type(4))) float f32x4;

__device__ __forceinline__ short f2bf(float f) {
  unsigned u = __builtin_bit_cast(unsigned, f);
  u += 0x7fffu + ((u >> 16) & 1u);
  return (short)(u >> 16);
}

// barrier that drains LDS (lgkmcnt) but leaves global loads (vmcnt) in flight
__device__ __forceinline__ void barlds() {
  asm volatile("s_waitcnt lgkmcnt(0)" ::: "memory");
  __builtin_amdgcn_s_barrier();
  asm volatile("" ::: "memory");
}

// ---------------- K0: weights -> bf16 fragment layouts ----------------------
__global__ __launch_bounds__(256) void k_prep(
    const float* __restrict__ Wq, const float* __restrict__ Wk,
    const float* __restrict__ Wv, const float* __restrict__ Wsk,
    const float* __restrict__ We,
    short* __restrict__ Btfrag, short* __restrict__ Wefrag)
{
  int idx = blockIdx.x * 256 + threadIdx.x;
  if (idx < 65536) {
    int b = idx & 7, lane = (idx >> 3) & 63, kt = (idx >> 9) & 3, tn = (idx >> 11) & 7, cb = idx >> 14;
    int k = kt * 32 + (lane >> 4) * 8 + b;
    int c = tn * 16 + (lane & 15);
    const float* W = cb == 0 ? Wq : cb == 1 ? Wk : cb == 2 ? Wv : Wsk;
    Btfrag[idx] = f2bf(W[k * 128 + c]);
  } else if (idx < 98304) {
    int i2 = idx - 65536;
    int b = i2 & 7, lane = (i2 >> 3) & 63, kt = (i2 >> 9) & 7, strip = i2 >> 12;
    int k = kt * 32 + (lane >> 4) * 8 + b;
    int c = strip * 16 + (lane & 15);
    Wefrag[i2] = f2bf(We[k * 128 + c]);
  }
}

// ---------------- K1: f32 -> bf16 stream cast (used for x and msg) ----------
__global__ __launch_bounds__(256) void k_xcast(const float* __restrict__ x,
                                               unsigned short* __restrict__ xb)
{
  size_t base = ((size_t)blockIdx.x * 256 + threadIdx.x) * 8;
  f32x4 a = *(const f32x4*)(x + base);
  f32x4 b = *(const f32x4*)(x + base + 4);
  short8v w;
  #pragma unroll
  for (int j = 0; j < 4; ++j) { w[j] = f2bf(a[j]); w[4 + j] = f2bf(b[j]); }
  *(short8v*)(xb + base) = w;
}

__global__ __launch_bounds__(256) void k_zero(int* __restrict__ p, int n)
{
  int i = blockIdx.x * 256 + threadIdx.x;
  if (i < n) p[i] = 0;
}

// ---------------- counting sort by dst --------------------------------------
__global__ __launch_bounds__(256) void k_hist(const int* __restrict__ ei, int* __restrict__ cnt)
{
  int e = blockIdx.x * 256 + threadIdx.x;
  if (e < EE) atomicAdd(&cnt[ei[EE + e]], 1);
}

__global__ __launch_bounds__(256) void k_scan_a(const int* __restrict__ cnt,
    int* __restrict__ offtmp, int* __restrict__ bsum)
{
  __shared__ int sc[256];
  int t = threadIdx.x;
  int i = blockIdx.x * 256 + t;
  int v = (i < NN) ? cnt[i] : 0;
  sc[t] = v;
  __syncthreads();
  for (int d = 1; d < 256; d <<= 1) {
    int add = (t >= d) ? sc[t - d] : 0;
    __syncthreads();
    sc[t] += add;
    __syncthreads();
  }
  if (i < NN) offtmp[i] = sc[t] - v;
  if (t == 255) bsum[blockIdx.x] = sc[255];
}

__global__ __launch_bounds__(512) void k_scan_b(const int* __restrict__ bsum,
                                                int* __restrict__ bbase)
{
  __shared__ int sc[512];
  int t = threadIdx.x;
  int v = (t < 391) ? bsum[t] : 0;
  sc[t] = v;
  __syncthreads();
  for (int d = 1; d < 512; d <<= 1) {
    int add = (t >= d) ? sc[t - d] : 0;
    __syncthreads();
    sc[t] += add;
    __syncthreads();
  }
  bbase[t] = sc[t] - v;
}

// ---------------- K_scatter: counting-sort scatter + fused emeta pack -------
__global__ __launch_bounds__(256) void k_scatter(const int* __restrict__ ei,
    const float* __restrict__ tt, const float* __restrict__ lu,
    const int* __restrict__ offtmp, const int* __restrict__ bbase,
    int* __restrict__ cur, int4* __restrict__ emeta)
{
  int e = blockIdx.x * 256 + threadIdx.x;
  if (e < EE) {
    int d = ei[EE + e];
    int pos = offtmp[d] + bbase[d >> 8] + atomicAdd(&cur[d], 1);
    int sv = ei[e];
    int4 m;
    m.x = e; m.y = sv; m.z = d;
    m.w = __float_as_int(tt[e] - lu[sv]);
    emeta[pos] = m;
  }
}

// ---------------- K_main: 64 dst/block; MFMA S/PV; aliased LDS, 2 blk/CU ----
// Region R (24576 shorts = 48KB), two configurations per tile:
//   staging/MFMA-read:  XS = R[0:8192)   rows el*128 ; EAT = R[8192:24576) rows el*256
//   post-B0:            KL = R[0:8192)   rows e*128  ; VT = R[8192:16384) [ch][64]
//                       PLm = R[16384:20480) ; PLm2 = R[20480:24576)
// (512,4): 128-unified-reg budget. This LEAN templated instantiation (no f32
// fallback, no skp regs) is the占 attempt to fit without the r10 scratch spill.
// Diagnostic: VGPR~96-112 + FETCH~160MB = success; VGPR=64 + FETCH>0.5GB = spill.
template<int USE_MP>
__global__ __launch_bounds__(512, 4) void k_main(
    const unsigned short* __restrict__ xb, const float* __restrict__ msg,
    const unsigned short* __restrict__ msgb,
    const float* __restrict__ tw, const float* __restrict__ tb,
    const short* __restrict__ Btfrag, const short* __restrict__ Wefrag,
    const float* __restrict__ bq, const float* __restrict__ bk,
    const float* __restrict__ bv, const float* __restrict__ bsk,
    const int* __restrict__ offtmp, const int* __restrict__ bbase,
    const int4* __restrict__ emeta, float* __restrict__ out)
{
  __shared__ short R[24576];
  __shared__ short QL[64 * 128];
  __shared__ float sdenL[128];
  __shared__ int dslot[64];

  short* const XS = R;
  short* const EAT = R + 8192;
  short* const KL = R;
  short* const VT = R + 8192;
  short* const PLm = R + 16384;
  short* const PLm2 = R + 20480;

  const int tid = threadIdx.x;
  const int nb0 = blockIdx.x * 64;
  const int wid = tid >> 6, lane = tid & 63;
  const int g = lane >> 4, lr = lane & 15, l7 = lr & 7;
  const int el = tid >> 3, p = tid & 7;
  const int er7 = el & 7;
  const int psw = p ^ er7;           // physical slot for natural chunk p
  const int cme = wid * 16 + lr;
  const int cmeh = cme >> 3, cml = cme & 7;

  const float bqc = bq[cme], bkc = bk[cme], bvc = bv[cme], bskc = bsk[cme];
  const short8v ONEB = {16256,16256,16256,16256,16256,16256,16256,16256}; // bf16 1.0

  // ---- prologue: stage dst-node x -> XS (store-side swizzle)
  {
    int node = nb0 + el;
    short8v a = {0,0,0,0,0,0,0,0}, b = a;
    if (node < NN) {
      const unsigned short* xp = xb + (size_t)node * 128 + p * 8;
      a = *(const short8v*)xp;
      b = *(const short8v*)(xp + 64);
    }
    *(short8v*)&XS[el * 128 + psw * 8] = a;
    *(short8v*)&XS[el * 128 + psw * 8 + 64] = b;
  }
  barlds();
  // ---- prologue: q -> QL (swizzled bf16), skip -> out (re-read at epilogue)
  {
    f32x4 qacc[4], skacc[4];
    #pragma unroll
    for (int eg = 0; eg < 4; ++eg) {
      qacc[eg] = (f32x4){0.f, 0.f, 0.f, 0.f};
      skacc[eg] = qacc[eg];
    }
    #pragma unroll
    for (int kt = 0; kt < 4; ++kt) {
      short8v bqf = *(const short8v*)(Btfrag + (size_t)(((0 + wid) * 4 + kt) * 64 + lane) * 8);
      short8v bsf = *(const short8v*)(Btfrag + (size_t)(((24 + wid) * 4 + kt) * 64 + lane) * 8);
      const int sw = (((kt << 2) | g) ^ l7) << 3;
      #pragma unroll
      for (int eg = 0; eg < 4; ++eg) {
        const short8v a = *(const short8v*)&XS[(eg * 16 + lr) * 128 + sw];
        qacc[eg] = __builtin_amdgcn_mfma_f32_16x16x32_bf16(a, bqf, qacc[eg], 0, 0, 0);
        skacc[eg] = __builtin_amdgcn_mfma_f32_16x16x32_bf16(a, bsf, skacc[eg], 0, 0, 0);
      }
    }
    #pragma unroll
    for (int eg = 0; eg < 4; ++eg)
      #pragma unroll
      for (int rg = 0; rg < 4; ++rg) {
        int row = eg * 16 + g * 4 + rg;
        int node = nb0 + row;
        QL[row * 128 + ((cmeh ^ (row & 7)) << 3) + cml] = f2bf(qacc[eg][rg] + bqc);
        if (node < NN) out[(size_t)node * 128 + cme] = skacc[eg][rg] + bskc;
      }
  }

  const int beg = offtmp[nb0] + bbase[nb0 >> 8];
  const int end = (nb0 + 64 < NN) ? (offtmp[nb0 + 64] + bbase[(nb0 + 64) >> 8]) : EE;

  // persistent accumulators
  f32x4 acc[4], sdacc;
  #pragma unroll
  for (int rtt = 0; rtt < 4; ++rtt) acc[rtt] = (f32x4){0.f, 0.f, 0.f, 0.f};
  sdacc = (f32x4){0.f, 0.f, 0.f, 0.f};

  // prefetch tile 0 (natural chunks p, p+8)
  int pdst = 0; float prelt = 0.f; bool pval = false;
  short8v px0 = {0,0,0,0,0,0,0,0}, px1 = px0, pmb0 = px0, pmb1 = px0;
  {
    int i = beg + el;
    pval = i < end;
    if (pval) {
      int4 m = emeta[i];
      pdst = m.z; prelt = __int_as_float(m.w);
      const unsigned short* xp = xb + (size_t)m.y * 128 + p * 8;
      px0 = *(const short8v*)xp;
      px1 = *(const short8v*)(xp + 64);
      if constexpr (USE_MP) {
        const unsigned short* mp = msgb + (size_t)m.x * 128 + p * 8;
        pmb0 = *(const short8v*)mp;
        pmb1 = *(const short8v*)(mp + 64);
      } else {
        const float* mp = msg + (size_t)m.x * 128 + p * 8;
        f32x4 m0 = *(const f32x4*)mp,        m1 = *(const f32x4*)(mp + 4);
        f32x4 m2 = *(const f32x4*)(mp + 64), m3 = *(const f32x4*)(mp + 68);
        #pragma unroll
        for (int j = 0; j < 4; ++j) {
          pmb0[j] = f2bf(m0[j]); pmb0[4 + j] = f2bf(m1[j]);
          pmb1[j] = f2bf(m2[j]); pmb1[4 + j] = f2bf(m3[j]);
        }
      }
    }
  }
  barlds();   // QL visible; R free (acts as barrier D for tile -1)

  for (int t0 = beg; t0 < end; t0 += 64) {
    // ---- S0: commit prefetched tile (XS + EAT + dslot), store-side swizzle
    if (p == 0) dslot[el] = pval ? (pdst - nb0) : -1;
    *(short8v*)&XS[el * 128 + psw * 8] = px0;
    *(short8v*)&XS[el * 128 + psw * 8 + 64] = px1;
    *(short8v*)&EAT[el * 256 + 128 + psw * 8] = pmb0;
    *(short8v*)&EAT[el * 256 + 128 + psw * 8 + 64] = pmb1;
    {
      f32x4 w0 = *(const f32x4*)(tw + p * 8),      w1 = *(const f32x4*)(tw + p * 8 + 4);
      f32x4 b0 = *(const f32x4*)(tb + p * 8),      b1 = *(const f32x4*)(tb + p * 8 + 4);
      f32x4 w2 = *(const f32x4*)(tw + p * 8 + 64), w3 = *(const f32x4*)(tw + p * 8 + 68);
      f32x4 b2 = *(const f32x4*)(tb + p * 8 + 64), b3 = *(const f32x4*)(tb + p * 8 + 68);
      short8v ta, tb2;
      #pragma unroll
      for (int j = 0; j < 4; ++j) {
        ta[j]      = f2bf(__cosf(fmaf(prelt, w0[j], b0[j])));
        ta[4 + j]  = f2bf(__cosf(fmaf(prelt, w1[j], b1[j])));
        tb2[j]     = f2bf(__cosf(fmaf(prelt, w2[j], b2[j])));
        tb2[4 + j] = f2bf(__cosf(fmaf(prelt, w3[j], b3[j])));
      }
      *(short8v*)&EAT[el * 256 + psw * 8] = ta;
      *(short8v*)&EAT[el * 256 + psw * 8 + 64] = tb2;
    }
    barlds();   // barrier A

    // ---- prefetch next tile
    {
      int i = t0 + 64 + el;
      pval = i < end;
      if (pval) {
        int4 m = emeta[i];
        pdst = m.z; prelt = __int_as_float(m.w);
        const unsigned short* xp = xb + (size_t)m.y * 128 + p * 8;
        px0 = *(const short8v*)xp;
        px1 = *(const short8v*)(xp + 64);
        if constexpr (USE_MP) {
          const unsigned short* mp = msgb + (size_t)m.x * 128 + p * 8;
          pmb0 = *(const short8v*)mp;
          pmb1 = *(const short8v*)(mp + 64);
        } else {
          const float* mp = msg + (size_t)m.x * 128 + p * 8;
          f32x4 m0 = *(const f32x4*)mp,        m1 = *(const f32x4*)(mp + 4);
          f32x4 m2 = *(const f32x4*)(mp + 64), m3 = *(const f32x4*)(mp + 68);
          #pragma unroll
          for (int j = 0; j < 4; ++j) {
            pmb0[j] = f2bf(m0[j]); pmb0[4 + j] = f2bf(m1[j]);
            pmb1[j] = f2bf(m2[j]); pmb1[4 + j] = f2bf(m3[j]);
          }
        }
      }
    }

    // ---- e = [TE|msg] @ We  (K=256)
    f32x4 ae[4];
    ae[0] = (f32x4){0.f, 0.f, 0.f, 0.f}; ae[1] = ae[0]; ae[2] = ae[0]; ae[3] = ae[0];
    #pragma unroll
    for (int kt = 0; kt < 8; ++kt) {
      short8v wef = *(const short8v*)(Wefrag + (size_t)((wid * 8 + kt) * 64 + lane) * 8);
      const int sw = (((kt << 2) | g) ^ l7) << 3;
      #pragma unroll
      for (int eg = 0; eg < 4; ++eg) {
        const short8v a = *(const short8v*)&EAT[(eg * 16 + lr) * 256 + sw];
        ae[eg] = __builtin_amdgcn_mfma_f32_16x16x32_bf16(a, wef, ae[eg], 0, 0, 0);
      }
    }
    // ---- k, v = x[src] @ Wk/Wv (shared A reads)
    f32x4 ak[4], av[4];
    ak[0] = (f32x4){0.f, 0.f, 0.f, 0.f}; ak[1] = ak[0]; ak[2] = ak[0]; ak[3] = ak[0];
    av[0] = ak[0]; av[1] = ak[0]; av[2] = ak[0]; av[3] = ak[0];
    #pragma unroll
    for (int kt = 0; kt < 4; ++kt) {
      short8v wkf = *(const short8v*)(Btfrag + (size_t)(((8 + wid) * 4 + kt) * 64 + lane) * 8);
      short8v wvf = *(const short8v*)(Btfrag + (size_t)(((16 + wid) * 4 + kt) * 64 + lane) * 8);
      const int sw = (((kt << 2) | g) ^ l7) << 3;
      #pragma unroll
      for (int eg = 0; eg < 4; ++eg) {
        const short8v a = *(const short8v*)&XS[(eg * 16 + lr) * 128 + sw];
        ak[eg] = __builtin_amdgcn_mfma_f32_16x16x32_bf16(a, wkf, ak[eg], 0, 0, 0);
        av[eg] = __builtin_amdgcn_mfma_f32_16x16x32_bf16(a, wvf, av[eg], 0, 0, 0);
      }
    }
    barlds();   // barrier B0 — XS/EAT dead, region becomes KL/VT/PLm

    // ---- write khat -> KL (row swz), vhat -> VT ([ch][edge], edge-chunk swz)
    #pragma unroll
    for (int eg = 0; eg < 4; ++eg)
      #pragma unroll
      for (int rg = 0; rg < 4; ++rg) {
        int e = eg * 16 + g * 4 + rg;
        float kh = ak[eg][rg] + bkc + ae[eg][rg];
        float vh = av[eg][rg] + bvc + ae[eg][rg];
        KL[e * 128 + ((cmeh ^ (e & 7)) << 3) + cml] = f2bf(kh);
        VT[cme * 64 + ((((e >> 3) ^ cml)) << 3) + (e & 7)] = f2bf(vh);
      }
    barlds();   // barrier B

    // ---- S = Q @ Khat^T PER HEAD (head0: kt 0,1; head1: kt 2,3)
    {
      const int rt = wid >> 1, ct0 = (wid & 1) * 2;
      short8v qa[4];
      #pragma unroll
      for (int kt = 0; kt < 4; ++kt)
        qa[kt] = *(const short8v*)&QL[(rt * 16 + lr) * 128 + ((((kt << 2) | g) ^ l7) << 3)];
      #pragma unroll
      for (int c2 = 0; c2 < 2; ++c2) {
        const int ct = ct0 + c2;
        f32x4 s0 = (f32x4){0.f, 0.f, 0.f, 0.f};
        f32x4 s1 = (f32x4){0.f, 0.f, 0.f, 0.f};
        #pragma unroll
        for (int kt = 0; kt < 4; ++kt) {
          const short8v kbf = *(const short8v*)&KL[(ct * 16 + lr) * 128 + ((((kt << 2) | g) ^ l7) << 3)];
          if (kt < 2) s0 = __builtin_amdgcn_mfma_f32_16x16x32_bf16(qa[kt], kbf, s0, 0, 0, 0);
          else        s1 = __builtin_amdgcn_mfma_f32_16x16x32_bf16(qa[kt], kbf, s1, 0, 0, 0);
        }
        const int col = ct * 16 + lr;
        const int dsc = dslot[col];
        #pragma unroll
        for (int rg = 0; rg < 4; ++rg) {
          int row = rt * 16 + g * 4 + rg;
          bool hit = (dsc == row);
          float pv0 = hit ? __expf(s0[rg] * 0.125f) : 0.f;
          float pv1 = hit ? __expf(s1[rg] * 0.125f) : 0.f;
          int off = row * 64 + ((((col >> 3) ^ (row & 7))) << 3) + (col & 7);
          PLm[off] = f2bf(pv0);
          PLm2[off] = f2bf(pv1);
        }
      }
    }
    barlds();   // barrier C

    // ---- PV: acc += P_head @ Vhat ; sden per head via ones-B
    {
      const short* PH = (wid < 4) ? PLm : PLm2;
      const int rt4 = wid & 3;
      const short8v vb0 = *(const short8v*)&VT[cme * 64 + ((g ^ cml) << 3)];
      const short8v vb1 = *(const short8v*)&VT[cme * 64 + (((4 | g) ^ cml) << 3)];
      #pragma unroll
      for (int rtt = 0; rtt < 4; ++rtt) {
        const short8v pa0 = *(const short8v*)&PH[(rtt * 16 + lr) * 64 + ((g ^ l7) << 3)];
        const short8v pa1 = *(const short8v*)&PH[(rtt * 16 + lr) * 64 + (((4 | g) ^ l7) << 3)];
        acc[rtt] = __builtin_amdgcn_mfma_f32_16x16x32_bf16(pa0, vb0, acc[rtt], 0, 0, 0);
        acc[rtt] = __builtin_amdgcn_mfma_f32_16x16x32_bf16(pa1, vb1, acc[rtt], 0, 0, 0);
        if (rt4 == rtt) {
          sdacc = __builtin_amdgcn_mfma_f32_16x16x32_bf16(pa0, ONEB, sdacc, 0, 0, 0);
          sdacc = __builtin_amdgcn_mfma_f32_16x16x32_bf16(pa1, ONEB, sdacc, 0, 0, 0);
        }
      }
    }
    barlds();   // barrier D — PV done, R may be restaged
  }

  // ---- epilogue: sden to LDS (per head), then out += acc / (sden + eps)
  if (lr == 0) {
    #pragma unroll
    for (int rg = 0; rg < 4; ++rg)
      sdenL[(wid >> 2) * 64 + (wid & 3) * 16 + g * 4 + rg] = sdacc[rg];
  }
  barlds();
  #pragma unroll
  for (int rtt = 0; rtt < 4; ++rtt)
    #pragma unroll
    for (int rg = 0; rg < 4; ++rg) {
      int row = rtt * 16 + g * 4 + rg;
      int node = nb0 + row;
      if (node < NN) {
        float den = sdenL[(wid >> 2) * 64 + row] + 1e-16f;
        size_t o = (size_t)node * 128 + cme;
        out[o] = out[o] + acc[rtt][rg] / den;
      }
    }
}

extern "C" void kernel_launch(void* const* d_in, const int* in_sizes, int n_in,
                              void* d_out, int out_size, void* d_ws, size_t ws_size,
                              hipStream_t stream) {
  const float* x    = (const float*)d_in[0];
  const float* lu   = (const float*)d_in[1];
  const float* tt   = (const float*)d_in[2];
  const float* msg  = (const float*)d_in[3];
  const int*   ei   = (const int*)d_in[4];
  const float* timew = (const float*)d_in[5];
  const float* timeb = (const float*)d_in[6];
  const float* Wq   = (const float*)d_in[7];
  const float* bq   = (const float*)d_in[8];
  const float* Wk   = (const float*)d_in[9];
  const float* bk   = (const float*)d_in[10];
  const float* Wv   = (const float*)d_in[11];
  const float* bv   = (const float*)d_in[12];
  const float* We   = (const float*)d_in[13];
  const float* Wsk  = (const float*)d_in[14];
  const float* bsk  = (const float*)d_in[15];
  float* out = (float*)d_out;

  char* wsp = (char*)d_ws;
  unsigned short* xbw  = (unsigned short*)wsp;
  short* Btfrag = (short*)(wsp + 51200000);
  short* Wefrag = (short*)(wsp + 51331072);
  int* cnt      = (int*)(wsp + 51404800);
  int* cur      = (int*)(wsp + 51804800);
  int* offtmp   = (int*)(wsp + 52204800);
  int* bsum     = (int*)(wsp + 52605184);
  int* bbase    = (int*)(wsp + 52607232);
  int4* emeta   = (int4*)(wsp + 54609280);
  unsigned short* msgb = (unsigned short*)(wsp + 62609280);
  const int use_mp = (ws_size >= (size_t)190609280) ? 1 : 0;

  k_zero<<<782, 256, 0, stream>>>(cnt, 200000);           // cnt + cur
  k_prep<<<384, 256, 0, stream>>>(Wq, Wk, Wv, Wsk, We, Btfrag, Wefrag);
  k_xcast<<<6250, 256, 0, stream>>>(x, xbw);
  if (use_mp) k_xcast<<<31250, 256, 0, stream>>>(msg, msgb);
  k_hist<<<1954, 256, 0, stream>>>(ei, cnt);
  k_scan_a<<<391, 256, 0, stream>>>(cnt, offtmp, bsum);
  k_scan_b<<<1, 512, 0, stream>>>(bsum, bbase);
  k_scatter<<<1954, 256, 0, stream>>>(ei, tt, lu, offtmp, bbase, cur, emeta);
  if (use_mp) {
    k_main<1><<<1563, 512, 0, stream>>>(xbw, msg, msgb, timew, timeb,
                                        Btfrag, Wefrag, bq, bk, bv, bsk,
                                        offtmp, bbase, emeta, out);
  } else {
    k_main<0><<<1563, 512, 0, stream>>>(xbw, msg, msgb, timew, timeb,
                                        Btfrag, Wefrag, bq, bk, bv, bsk,
                                        offtmp, bbase, emeta, out);
  }
}

// Round 18
// 417.839 us; speedup vs baseline: 2.0663x; 2.0663x over previous
//
#include <hip/hip_runtime.h>
#include <hip/hip_bf16.h>

#define NN 100000
#define EE 500000

typedef __attribute__((ext_vector_type(8))) short short8v;
typedef __attribute__((ext_vector_type(4))) float f32x4;

__device__ __forceinline__ short f2bf(float f) {
  unsigned u = __builtin_bit_cast(unsigned, f);
  u += 0x7fffu + ((u >> 16) & 1u);
  return (short)(u >> 16);
}

// barrier that drains LDS (lgkmcnt) but leaves global loads (vmcnt) in flight
__device__ __forceinline__ void barlds() {
  asm volatile("s_waitcnt lgkmcnt(0)" ::: "memory");
  __builtin_amdgcn_s_barrier();
  asm volatile("" ::: "memory");
}

// ---------------- K0: weights -> bf16 fragment layouts ----------------------
__global__ __launch_bounds__(256) void k_prep(
    const float* __restrict__ Wq, const float* __restrict__ Wk,
    const float* __restrict__ Wv, const float* __restrict__ Wsk,
    const float* __restrict__ We,
    short* __restrict__ Btfrag, short* __restrict__ Wefrag)
{
  int idx = blockIdx.x * 256 + threadIdx.x;
  if (idx < 65536) {
    int b = idx & 7, lane = (idx >> 3) & 63, kt = (idx >> 9) & 3, tn = (idx >> 11) & 7, cb = idx >> 14;
    int k = kt * 32 + (lane >> 4) * 8 + b;
    int c = tn * 16 + (lane & 15);
    const float* W = cb == 0 ? Wq : cb == 1 ? Wk : cb == 2 ? Wv : Wsk;
    Btfrag[idx] = f2bf(W[k * 128 + c]);
  } else if (idx < 98304) {
    int i2 = idx - 65536;
    int b = i2 & 7, lane = (i2 >> 3) & 63, kt = (i2 >> 9) & 7, strip = i2 >> 12;
    int k = kt * 32 + (lane >> 4) * 8 + b;
    int c = strip * 16 + (lane & 15);
    Wefrag[i2] = f2bf(We[k * 128 + c]);
  }
}

// ---------------- K1: f32 -> bf16 stream cast (used for x and msg) ----------
__global__ __launch_bounds__(256) void k_xcast(const float* __restrict__ x,
                                               unsigned short* __restrict__ xb)
{
  size_t base = ((size_t)blockIdx.x * 256 + threadIdx.x) * 8;
  f32x4 a = *(const f32x4*)(x + base);
  f32x4 b = *(const f32x4*)(x + base + 4);
  short8v w;
  #pragma unroll
  for (int j = 0; j < 4; ++j) { w[j] = f2bf(a[j]); w[4 + j] = f2bf(b[j]); }
  *(short8v*)(xb + base) = w;
}

__global__ __launch_bounds__(256) void k_zero(int* __restrict__ p, int n)
{
  int i = blockIdx.x * 256 + threadIdx.x;
  if (i < n) p[i] = 0;
}

// ---------------- counting sort by dst --------------------------------------
__global__ __launch_bounds__(256) void k_hist(const int* __restrict__ ei, int* __restrict__ cnt)
{
  int e = blockIdx.x * 256 + threadIdx.x;
  if (e < EE) atomicAdd(&cnt[ei[EE + e]], 1);
}

__global__ __launch_bounds__(256) void k_scan_a(const int* __restrict__ cnt,
    int* __restrict__ offtmp, int* __restrict__ bsum)
{
  __shared__ int sc[256];
  int t = threadIdx.x;
  int i = blockIdx.x * 256 + t;
  int v = (i < NN) ? cnt[i] : 0;
  sc[t] = v;
  __syncthreads();
  for (int d = 1; d < 256; d <<= 1) {
    int add = (t >= d) ? sc[t - d] : 0;
    __syncthreads();
    sc[t] += add;
    __syncthreads();
  }
  if (i < NN) offtmp[i] = sc[t] - v;
  if (t == 255) bsum[blockIdx.x] = sc[255];
}

__global__ __launch_bounds__(512) void k_scan_b(const int* __restrict__ bsum,
                                                int* __restrict__ bbase)
{
  __shared__ int sc[512];
  int t = threadIdx.x;
  int v = (t < 391) ? bsum[t] : 0;
  sc[t] = v;
  __syncthreads();
  for (int d = 1; d < 512; d <<= 1) {
    int add = (t >= d) ? sc[t - d] : 0;
    __syncthreads();
    sc[t] += add;
    __syncthreads();
  }
  bbase[t] = sc[t] - v;
}

// ---------------- K_scatter: counting-sort scatter + fused emeta pack -------
__global__ __launch_bounds__(256) void k_scatter(const int* __restrict__ ei,
    const float* __restrict__ tt, const float* __restrict__ lu,
    const int* __restrict__ offtmp, const int* __restrict__ bbase,
    int* __restrict__ cur, int4* __restrict__ emeta)
{
  int e = blockIdx.x * 256 + threadIdx.x;
  if (e < EE) {
    int d = ei[EE + e];
    int pos = offtmp[d] + bbase[d >> 8] + atomicAdd(&cur[d], 1);
    int sv = ei[e];
    int4 m;
    m.x = e; m.y = sv; m.z = d;
    m.w = __float_as_int(tt[e] - lu[sv]);
    emeta[pos] = m;
  }
}

// ---------------- K_main: 64 dst/block; MFMA S/PV; aliased LDS --------------
// Region R (24576 shorts = 48KB), two configurations per tile:
//   staging/MFMA-read:  XS = R[0:8192)   rows el*128 ; EAT = R[8192:24576) rows el*256
//   post-B0:            KL = R[0:8192)   rows e*128  ; VT = R[8192:16384) [ch][64]
//                       PLm = R[16384:20480) ; PLm2 = R[20480:24576)
// NOTE: plain __launch_bounds__(512) — min-waves clause (r4/r10/r17) always
// triggers a 64/64 VGPR/AGPR split + ~1GB scratch spill; persistent weight
// regs (r12) spill too. Weights stream from L2 per tile (hidden; r11==r9).
// Chunk-XOR swizzle with stride 128/64 is conflict-free on fragment reads
// (slot = C7^(lr&7) bijection); padding BREAKS it (r15: conflicts 4x).
template<int USE_MP>
__global__ __launch_bounds__(512) void k_main(
    const unsigned short* __restrict__ xb, const float* __restrict__ msg,
    const unsigned short* __restrict__ msgb,
    const float* __restrict__ tw, const float* __restrict__ tb,
    const short* __restrict__ Btfrag, const short* __restrict__ Wefrag,
    const float* __restrict__ bq, const float* __restrict__ bk,
    const float* __restrict__ bv, const float* __restrict__ bsk,
    const int* __restrict__ offtmp, const int* __restrict__ bbase,
    const int4* __restrict__ emeta, float* __restrict__ out)
{
  __shared__ short R[24576];
  __shared__ short QL[64 * 128];
  __shared__ float sdenL[128];
  __shared__ int dslot[64];

  short* const XS = R;
  short* const EAT = R + 8192;
  short* const KL = R;
  short* const VT = R + 8192;
  short* const PLm = R + 16384;
  short* const PLm2 = R + 20480;

  const int tid = threadIdx.x;
  const int nb0 = blockIdx.x * 64;
  const int wid = tid >> 6, lane = tid & 63;
  const int g = lane >> 4, lr = lane & 15, l7 = lr & 7;
  const int el = tid >> 3, p = tid & 7;
  const int er7 = el & 7;
  const int psw = p ^ er7;           // physical slot for natural chunk p
  const int cme = wid * 16 + lr;
  const int cmeh = cme >> 3, cml = cme & 7;

  const float bqc = bq[cme], bkc = bk[cme], bvc = bv[cme], bskc = bsk[cme];
  const short8v ONEB = {16256,16256,16256,16256,16256,16256,16256,16256}; // bf16 1.0

  // ---- prologue: stage dst-node x -> XS (store-side swizzle)
  {
    int node = nb0 + el;
    short8v a = {0,0,0,0,0,0,0,0}, b = a;
    if (node < NN) {
      const unsigned short* xp = xb + (size_t)node * 128 + p * 8;
      a = *(const short8v*)xp;
      b = *(const short8v*)(xp + 64);
    }
    *(short8v*)&XS[el * 128 + psw * 8] = a;
    *(short8v*)&XS[el * 128 + psw * 8 + 64] = b;
  }
  barlds();
  // ---- prologue: q -> QL (swizzled bf16); skip stays in registers
  f32x4 skp[4];
  {
    f32x4 qacc[4];
    #pragma unroll
    for (int eg = 0; eg < 4; ++eg) {
      qacc[eg] = (f32x4){0.f, 0.f, 0.f, 0.f};
      skp[eg] = qacc[eg];
    }
    #pragma unroll
    for (int kt = 0; kt < 4; ++kt) {
      short8v bqf = *(const short8v*)(Btfrag + (size_t)(((0 + wid) * 4 + kt) * 64 + lane) * 8);
      short8v bsf = *(const short8v*)(Btfrag + (size_t)(((24 + wid) * 4 + kt) * 64 + lane) * 8);
      const int sw = (((kt << 2) | g) ^ l7) << 3;
      #pragma unroll
      for (int eg = 0; eg < 4; ++eg) {
        const short8v a = *(const short8v*)&XS[(eg * 16 + lr) * 128 + sw];
        qacc[eg] = __builtin_amdgcn_mfma_f32_16x16x32_bf16(a, bqf, qacc[eg], 0, 0, 0);
        skp[eg] = __builtin_amdgcn_mfma_f32_16x16x32_bf16(a, bsf, skp[eg], 0, 0, 0);
      }
    }
    #pragma unroll
    for (int eg = 0; eg < 4; ++eg)
      #pragma unroll
      for (int rg = 0; rg < 4; ++rg) {
        int row = eg * 16 + g * 4 + rg;
        QL[row * 128 + ((cmeh ^ (row & 7)) << 3) + cml] = f2bf(qacc[eg][rg] + bqc);
      }
  }

  const int beg = offtmp[nb0] + bbase[nb0 >> 8];
  const int end = (nb0 + 64 < NN) ? (offtmp[nb0 + 64] + bbase[(nb0 + 64) >> 8]) : EE;

  // persistent accumulators
  f32x4 acc[4], sdacc;
  #pragma unroll
  for (int rtt = 0; rtt < 4; ++rtt) acc[rtt] = (f32x4){0.f, 0.f, 0.f, 0.f};
  sdacc = (f32x4){0.f, 0.f, 0.f, 0.f};

  // prefetch tile 0 (natural chunks p, p+8)
  int pdst = 0; float prelt = 0.f; bool pval = false;
  short8v px0 = {0,0,0,0,0,0,0,0}, px1 = px0, pmb0 = px0, pmb1 = px0;
  {
    int i = beg + el;
    pval = i < end;
    if (pval) {
      int4 m = emeta[i];
      pdst = m.z; prelt = __int_as_float(m.w);
      const unsigned short* xp = xb + (size_t)m.y * 128 + p * 8;
      px0 = *(const short8v*)xp;
      px1 = *(const short8v*)(xp + 64);
      if constexpr (USE_MP) {
        const unsigned short* mp = msgb + (size_t)m.x * 128 + p * 8;
        pmb0 = *(const short8v*)mp;
        pmb1 = *(const short8v*)(mp + 64);
      } else {
        const float* mp = msg + (size_t)m.x * 128 + p * 8;
        f32x4 m0 = *(const f32x4*)mp,        m1 = *(const f32x4*)(mp + 4);
        f32x4 m2 = *(const f32x4*)(mp + 64), m3 = *(const f32x4*)(mp + 68);
        #pragma unroll
        for (int j = 0; j < 4; ++j) {
          pmb0[j] = f2bf(m0[j]); pmb0[4 + j] = f2bf(m1[j]);
          pmb1[j] = f2bf(m2[j]); pmb1[4 + j] = f2bf(m3[j]);
        }
      }
    }
  }
  barlds();   // QL visible; R free (acts as barrier D for tile -1)

  for (int t0 = beg; t0 < end; t0 += 64) {
    // ---- S0: commit prefetched tile (XS + EAT + dslot), store-side swizzle
    if (p == 0) dslot[el] = pval ? (pdst - nb0) : -1;
    *(short8v*)&XS[el * 128 + psw * 8] = px0;
    *(short8v*)&XS[el * 128 + psw * 8 + 64] = px1;
    *(short8v*)&EAT[el * 256 + 128 + psw * 8] = pmb0;
    *(short8v*)&EAT[el * 256 + 128 + psw * 8 + 64] = pmb1;
    {
      f32x4 w0 = *(const f32x4*)(tw + p * 8),      w1 = *(const f32x4*)(tw + p * 8 + 4);
      f32x4 b0 = *(const f32x4*)(tb + p * 8),      b1 = *(const f32x4*)(tb + p * 8 + 4);
      f32x4 w2 = *(const f32x4*)(tw + p * 8 + 64), w3 = *(const f32x4*)(tw + p * 8 + 68);
      f32x4 b2 = *(const f32x4*)(tb + p * 8 + 64), b3 = *(const f32x4*)(tb + p * 8 + 68);
      short8v ta, tb2;
      #pragma unroll
      for (int j = 0; j < 4; ++j) {
        ta[j]      = f2bf(__cosf(fmaf(prelt, w0[j], b0[j])));
        ta[4 + j]  = f2bf(__cosf(fmaf(prelt, w1[j], b1[j])));
        tb2[j]     = f2bf(__cosf(fmaf(prelt, w2[j], b2[j])));
        tb2[4 + j] = f2bf(__cosf(fmaf(prelt, w3[j], b3[j])));
      }
      *(short8v*)&EAT[el * 256 + psw * 8] = ta;
      *(short8v*)&EAT[el * 256 + psw * 8 + 64] = tb2;
    }
    barlds();   // barrier A

    // ---- prefetch next tile
    {
      int i = t0 + 64 + el;
      pval = i < end;
      if (pval) {
        int4 m = emeta[i];
        pdst = m.z; prelt = __int_as_float(m.w);
        const unsigned short* xp = xb + (size_t)m.y * 128 + p * 8;
        px0 = *(const short8v*)xp;
        px1 = *(const short8v*)(xp + 64);
        if constexpr (USE_MP) {
          const unsigned short* mp = msgb + (size_t)m.x * 128 + p * 8;
          pmb0 = *(const short8v*)mp;
          pmb1 = *(const short8v*)(mp + 64);
        } else {
          const float* mp = msg + (size_t)m.x * 128 + p * 8;
          f32x4 m0 = *(const f32x4*)mp,        m1 = *(const f32x4*)(mp + 4);
          f32x4 m2 = *(const f32x4*)(mp + 64), m3 = *(const f32x4*)(mp + 68);
          #pragma unroll
          for (int j = 0; j < 4; ++j) {
            pmb0[j] = f2bf(m0[j]); pmb0[4 + j] = f2bf(m1[j]);
            pmb1[j] = f2bf(m2[j]); pmb1[4 + j] = f2bf(m3[j]);
          }
        }
      }
    }

    // ---- e = [TE|msg] @ We  (K=256)
    f32x4 ae[4];
    ae[0] = (f32x4){0.f, 0.f, 0.f, 0.f}; ae[1] = ae[0]; ae[2] = ae[0]; ae[3] = ae[0];
    #pragma unroll
    for (int kt = 0; kt < 8; ++kt) {
      short8v wef = *(const short8v*)(Wefrag + (size_t)((wid * 8 + kt) * 64 + lane) * 8);
      const int sw = (((kt << 2) | g) ^ l7) << 3;
      #pragma unroll
      for (int eg = 0; eg < 4; ++eg) {
        const short8v a = *(const short8v*)&EAT[(eg * 16 + lr) * 256 + sw];
        ae[eg] = __builtin_amdgcn_mfma_f32_16x16x32_bf16(a, wef, ae[eg], 0, 0, 0);
      }
    }
    // ---- k, v = x[src] @ Wk/Wv (shared A reads)
    f32x4 ak[4], av[4];
    ak[0] = (f32x4){0.f, 0.f, 0.f, 0.f}; ak[1] = ak[0]; ak[2] = ak[0]; ak[3] = ak[0];
    av[0] = ak[0]; av[1] = ak[0]; av[2] = ak[0]; av[3] = ak[0];
    #pragma unroll
    for (int kt = 0; kt < 4; ++kt) {
      short8v wkf = *(const short8v*)(Btfrag + (size_t)(((8 + wid) * 4 + kt) * 64 + lane) * 8);
      short8v wvf = *(const short8v*)(Btfrag + (size_t)(((16 + wid) * 4 + kt) * 64 + lane) * 8);
      const int sw = (((kt << 2) | g) ^ l7) << 3;
      #pragma unroll
      for (int eg = 0; eg < 4; ++eg) {
        const short8v a = *(const short8v*)&XS[(eg * 16 + lr) * 128 + sw];
        ak[eg] = __builtin_amdgcn_mfma_f32_16x16x32_bf16(a, wkf, ak[eg], 0, 0, 0);
        av[eg] = __builtin_amdgcn_mfma_f32_16x16x32_bf16(a, wvf, av[eg], 0, 0, 0);
      }
    }
    barlds();   // barrier B0 — XS/EAT dead, region becomes KL/VT/PLm

    // ---- write khat -> KL (row swz), vhat -> VT ([ch][edge], edge-chunk swz)
    #pragma unroll
    for (int eg = 0; eg < 4; ++eg)
      #pragma unroll
      for (int rg = 0; rg < 4; ++rg) {
        int e = eg * 16 + g * 4 + rg;
        float kh = ak[eg][rg] + bkc + ae[eg][rg];
        float vh = av[eg][rg] + bvc + ae[eg][rg];
        KL[e * 128 + ((cmeh ^ (e & 7)) << 3) + cml] = f2bf(kh);
        VT[cme * 64 + ((((e >> 3) ^ cml)) << 3) + (e & 7)] = f2bf(vh);
      }
    barlds();   // barrier B

    // ---- S = Q @ Khat^T PER HEAD (head0: kt 0,1; head1: kt 2,3)
    {
      const int rt = wid >> 1, ct0 = (wid & 1) * 2;
      short8v qa[4];
      #pragma unroll
      for (int kt = 0; kt < 4; ++kt)
        qa[kt] = *(const short8v*)&QL[(rt * 16 + lr) * 128 + ((((kt << 2) | g) ^ l7) << 3)];
      #pragma unroll
      for (int c2 = 0; c2 < 2; ++c2) {
        const int ct = ct0 + c2;
        f32x4 s0 = (f32x4){0.f, 0.f, 0.f, 0.f};
        f32x4 s1 = (f32x4){0.f, 0.f, 0.f, 0.f};
        #pragma unroll
        for (int kt = 0; kt < 4; ++kt) {
          const short8v kbf = *(const short8v*)&KL[(ct * 16 + lr) * 128 + ((((kt << 2) | g) ^ l7) << 3)];
          if (kt < 2) s0 = __builtin_amdgcn_mfma_f32_16x16x32_bf16(qa[kt], kbf, s0, 0, 0, 0);
          else        s1 = __builtin_amdgcn_mfma_f32_16x16x32_bf16(qa[kt], kbf, s1, 0, 0, 0);
        }
        const int col = ct * 16 + lr;
        const int dsc = dslot[col];
        #pragma unroll
        for (int rg = 0; rg < 4; ++rg) {
          int row = rt * 16 + g * 4 + rg;
          bool hit = (dsc == row);
          float pv0 = hit ? __expf(s0[rg] * 0.125f) : 0.f;
          float pv1 = hit ? __expf(s1[rg] * 0.125f) : 0.f;
          int off = row * 64 + ((((col >> 3) ^ (row & 7))) << 3) + (col & 7);
          PLm[off] = f2bf(pv0);
          PLm2[off] = f2bf(pv1);
        }
      }
    }
    barlds();   // barrier C

    // ---- PV: acc += P_head @ Vhat ; sden per head via ones-B
    {
      const short* PH = (wid < 4) ? PLm : PLm2;
      const int rt4 = wid & 3;
      const short8v vb0 = *(const short8v*)&VT[cme * 64 + ((g ^ cml) << 3)];
      const short8v vb1 = *(const short8v*)&VT[cme * 64 + (((4 | g) ^ cml) << 3)];
      #pragma unroll
      for (int rtt = 0; rtt < 4; ++rtt) {
        const short8v pa0 = *(const short8v*)&PH[(rtt * 16 + lr) * 64 + ((g ^ l7) << 3)];
        const short8v pa1 = *(const short8v*)&PH[(rtt * 16 + lr) * 64 + (((4 | g) ^ l7) << 3)];
        acc[rtt] = __builtin_amdgcn_mfma_f32_16x16x32_bf16(pa0, vb0, acc[rtt], 0, 0, 0);
        acc[rtt] = __builtin_amdgcn_mfma_f32_16x16x32_bf16(pa1, vb1, acc[rtt], 0, 0, 0);
        if (rt4 == rtt) {
          sdacc = __builtin_amdgcn_mfma_f32_16x16x32_bf16(pa0, ONEB, sdacc, 0, 0, 0);
          sdacc = __builtin_amdgcn_mfma_f32_16x16x32_bf16(pa1, ONEB, sdacc, 0, 0, 0);
        }
      }
    }
    barlds();   // barrier D — PV done, R may be restaged
  }

  // ---- epilogue: sden to LDS (per head), out = skip + acc/(sden+eps)
  if (lr == 0) {
    #pragma unroll
    for (int rg = 0; rg < 4; ++rg)
      sdenL[(wid >> 2) * 64 + (wid & 3) * 16 + g * 4 + rg] = sdacc[rg];
  }
  barlds();
  #pragma unroll
  for (int rtt = 0; rtt < 4; ++rtt)
    #pragma unroll
    for (int rg = 0; rg < 4; ++rg) {
      int row = rtt * 16 + g * 4 + rg;
      int node = nb0 + row;
      if (node < NN) {
        float den = sdenL[(wid >> 2) * 64 + row] + 1e-16f;
        out[(size_t)node * 128 + cme] = skp[rtt][rg] + bskc + acc[rtt][rg] / den;
      }
    }
}

extern "C" void kernel_launch(void* const* d_in, const int* in_sizes, int n_in,
                              void* d_out, int out_size, void* d_ws, size_t ws_size,
                              hipStream_t stream) {
  const float* x    = (const float*)d_in[0];
  const float* lu   = (const float*)d_in[1];
  const float* tt   = (const float*)d_in[2];
  const float* msg  = (const float*)d_in[3];
  const int*   ei   = (const int*)d_in[4];
  const float* timew = (const float*)d_in[5];
  const float* timeb = (const float*)d_in[6];
  const float* Wq   = (const float*)d_in[7];
  const float* bq   = (const float*)d_in[8];
  const float* Wk   = (const float*)d_in[9];
  const float* bk   = (const float*)d_in[10];
  const float* Wv   = (const float*)d_in[11];
  const float* bv   = (const float*)d_in[12];
  const float* We   = (const float*)d_in[13];
  const float* Wsk  = (const float*)d_in[14];
  const float* bsk  = (const float*)d_in[15];
  float* out = (float*)d_out;

  char* wsp = (char*)d_ws;
  // ws layout (bytes):
  //   [0,           25,600,000)  xb      (N*128 bf16)
  //   [51,200,000,  51,331,072)  Btfrag
  //   [51,331,072,  51,396,608)  Wefrag
  //   [51,404,800,  51,804,800)  cnt     (N i32)
  //   [51,804,800,  52,204,800)  cur     (N i32)
  //   [52,204,800,  52,605,184)  offtmp
  //   [52,605,184,  52,607,232)  bsum
  //   [52,607,232,  52,609,280)  bbase
  //   [54,609,280,  62,609,280)  emeta   (E int4)
  //   [62,609,280, 190,609,280)  msgb    (E*128 bf16, natural order) -- optional
  unsigned short* xbw  = (unsigned short*)wsp;
  short* Btfrag = (short*)(wsp + 51200000);
  short* Wefrag = (short*)(wsp + 51331072);
  int* cnt      = (int*)(wsp + 51404800);
  int* cur      = (int*)(wsp + 51804800);
  int* offtmp   = (int*)(wsp + 52204800);
  int* bsum     = (int*)(wsp + 52605184);
  int* bbase    = (int*)(wsp + 52607232);
  int4* emeta   = (int4*)(wsp + 54609280);
  unsigned short* msgb = (unsigned short*)(wsp + 62609280);
  const int use_mp = (ws_size >= (size_t)190609280) ? 1 : 0;

  k_zero<<<782, 256, 0, stream>>>(cnt, 200000);           // cnt + cur
  k_prep<<<384, 256, 0, stream>>>(Wq, Wk, Wv, Wsk, We, Btfrag, Wefrag);
  k_xcast<<<6250, 256, 0, stream>>>(x, xbw);
  if (use_mp) k_xcast<<<31250, 256, 0, stream>>>(msg, msgb);
  k_hist<<<1954, 256, 0, stream>>>(ei, cnt);
  k_scan_a<<<391, 256, 0, stream>>>(cnt, offtmp, bsum);
  k_scan_b<<<1, 512, 0, stream>>>(bsum, bbase);
  k_scatter<<<1954, 256, 0, stream>>>(ei, tt, lu, offtmp, bbase, cur, emeta);
  if (use_mp) {
    k_main<1><<<1563, 512, 0, stream>>>(xbw, msg, msgb, timew, timeb,
                                        Btfrag, Wefrag, bq, bk, bv, bsk,
                                        offtmp, bbase, emeta, out);
  } else {
    k_main<0><<<1563, 512, 0, stream>>>(xbw, msg, msgb, timew, timeb,
                                        Btfrag, Wefrag, bq, bk, bv, bsk,
                                        offtmp, bbase, emeta, out);
  }
}